// Round 2
// baseline (30139.594 us; speedup 1.0000x reference)
//
#include <hip/hip_runtime.h>
#include <hip/hip_bf16.h>
#include <math.h>

typedef __hip_bfloat16 bf16;

#define D_    768
#define M_    5
#define DS_   768
#define NH_   12
#define B_    8
#define V_    512
#define S_    128
#define T_    16
#define A_    8
#define DIN_  6144

// runtime-dtype load: bf=1 -> bf16, bf=0 -> fp32
__device__ __forceinline__ float ldx(const void* p, size_t i, int bf) {
    return bf ? __bfloat162float(((const bf16*)p)[i]) : ((const float*)p)[i];
}

// Decide whether raw inputs are bf16 or fp32. For bf16 data, the low 16 bits
// of each 32-bit word are a valid bf16 of ~N(0,1) data (exponent 90..150).
// For fp32 data they are mantissa bits (random exponent, ~24% in range).
__global__ void probe_dtype(const void* __restrict__ video, int* __restrict__ flag) {
    if (threadIdx.x == 0 && blockIdx.x == 0) {
        const unsigned* w = (const unsigned*)video;
        int ok = 0;
        for (int i = 0; i < 256; i++) {
            unsigned e = (w[i] >> 7) & 0xFF;
            if (e >= 90 && e <= 150) ok++;
        }
        flag[0] = (ok > 192) ? 1 : 0;
    }
}

// ---------------- generic GEMM: C = act(A @ W^T + bias) ----------------
// A: (M,K) row-major (raw input if araw, else fp32 ws). W: (N,K) native dtype.
// If !FINAL: raw split-K partials to C[(z*M+m)*N+n].
template<int ACT, bool FINAL>
__global__ __launch_bounds__(256)
void gemm_nt(const void* __restrict__ A, long aoff, int araw, int lda,
             const void* __restrict__ W, long woff, int ldw,
             const void* __restrict__ bias, long boff,
             float* __restrict__ C, int ldc,
             int M, int N, int K, int Z, const int* __restrict__ dtf)
{
    const int wbf = dtf[0];
    const int abf = araw ? wbf : 0;
    __shared__ __align__(16) float As[16][68];
    __shared__ __align__(16) float Ws[16][68];
    const int n0 = blockIdx.x * 64, m0 = blockIdx.y * 64;
    const int kchunk = K / Z;
    const int k0 = blockIdx.z * kchunk, k1 = k0 + kchunk;
    const int tid = threadIdx.x;
    const int ty = tid >> 4, tx = tid & 15;
    const int lr = tid >> 2, lc = (tid & 3) * 4;

    float acc[4][4];
#pragma unroll
    for (int i = 0; i < 4; i++)
#pragma unroll
        for (int j = 0; j < 4; j++) acc[i][j] = 0.f;

    for (int k = k0; k < k1; k += 16) {
        {   // A tile (64 m-rows x 16 k) -> As[kcol][row]
            int m = m0 + lr;
            float a0 = 0.f, a1 = 0.f, a2 = 0.f, a3 = 0.f;
            if (m < M) {
                size_t o = (size_t)aoff + (size_t)m * lda + (k + lc);
                a0 = ldx(A, o, abf); a1 = ldx(A, o + 1, abf);
                a2 = ldx(A, o + 2, abf); a3 = ldx(A, o + 3, abf);
            }
            As[lc][lr] = a0; As[lc + 1][lr] = a1; As[lc + 2][lr] = a2; As[lc + 3][lr] = a3;
        }
        {   // W tile (64 n-rows x 16 k) -> Ws[kcol][nrow]
            int n = n0 + lr;
            size_t o = (size_t)woff + (size_t)n * ldw + (k + lc);
            Ws[lc][lr] = ldx(W, o, wbf); Ws[lc + 1][lr] = ldx(W, o + 1, wbf);
            Ws[lc + 2][lr] = ldx(W, o + 2, wbf); Ws[lc + 3][lr] = ldx(W, o + 3, wbf);
        }
        __syncthreads();
#pragma unroll
        for (int kk = 0; kk < 16; kk++) {
            float4 av = *(const float4*)&As[kk][ty * 4];
            float4 wv = *(const float4*)&Ws[kk][tx * 4];
            float a[4] = {av.x, av.y, av.z, av.w};
            float w[4] = {wv.x, wv.y, wv.z, wv.w};
#pragma unroll
            for (int i = 0; i < 4; i++)
#pragma unroll
                for (int j = 0; j < 4; j++)
                    acc[i][j] = fmaf(a[i], w[j], acc[i][j]);
        }
        __syncthreads();
    }

#pragma unroll
    for (int i = 0; i < 4; i++) {
        int m = m0 + ty * 4 + i;
        if (m >= M) continue;
#pragma unroll
        for (int j = 0; j < 4; j++) {
            int n = n0 + tx * 4 + j;
            float v = acc[i][j];
            if (FINAL) {
                v += ldx(bias, boff + n, wbf);
                if (ACT == 1) v = fmaxf(v, 0.f);
                C[(size_t)m * ldc + n] = v;
            } else {
                C[((size_t)blockIdx.z * M + m) * N + n] = v;
            }
        }
    }
}

template<int ACT>
__global__ void reduce_bias_act(const float* __restrict__ part, const void* __restrict__ bias,
                                long boff, float* __restrict__ C, int M, int N, int Z,
                                const int* __restrict__ dtf)
{
    int idx = blockIdx.x * 256 + threadIdx.x;
    if (idx >= M * N) return;
    int n = idx % N;
    float s = 0.f;
    for (int z = 0; z < Z; z++) s += part[(size_t)z * M * N + idx];
    s += ldx(bias, boff + n, dtf[0]);
    if (ACT == 1) s = fmaxf(s, 0.f);
    C[idx] = s;
}

// ---------------- attention: s2v, one sample (q: S rows, kv: V rows) ----------------
__global__ __launch_bounds__(256)
void attn_s2v(const float* __restrict__ qp_b, const float* __restrict__ kp_l,
              const float* __restrict__ vp_l, float* __restrict__ out_b)
{
    int h = blockIdx.x;
    int tid = threadIdx.x;
    __shared__ float qv[64], sc[512], red[256], prt[4][64];
    const float* kb = kp_l + h * 64;
    const float* vb = vp_l + h * 64;
    for (int i = 0; i < S_; i++) {
        if (tid < 64) qv[tid] = qp_b[(size_t)i * D_ + h * 64 + tid];
        __syncthreads();
        for (int j = tid; j < V_; j += 256) {
            const float* kr = kb + (size_t)j * D_;
            float s = 0.f;
#pragma unroll
            for (int d = 0; d < 64; d++) s = fmaf(qv[d], kr[d], s);
            sc[j] = s * 0.125f;
        }
        __syncthreads();
        red[tid] = fmaxf(sc[tid], sc[tid + 256]);
        __syncthreads();
        for (int off = 128; off > 0; off >>= 1) {
            if (tid < off) red[tid] = fmaxf(red[tid], red[tid + off]);
            __syncthreads();
        }
        float mx = red[0];
        __syncthreads();
        float e0 = expf(sc[tid] - mx), e1 = expf(sc[tid + 256] - mx);
        sc[tid] = e0; sc[tid + 256] = e1;
        red[tid] = e0 + e1;
        __syncthreads();
        for (int off = 128; off > 0; off >>= 1) {
            if (tid < off) red[tid] += red[tid + off];
            __syncthreads();
        }
        float inv = 1.f / red[0];
        int q4 = tid >> 6, d = tid & 63;
        float acc = 0.f;
        const float* vq = vb + (size_t)(q4 * 128) * D_ + d;
        for (int j = 0; j < 128; j++) acc = fmaf(sc[q4 * 128 + j], vq[(size_t)j * D_], acc);
        prt[q4][d] = acc;
        __syncthreads();
        if (tid < 64)
            out_b[(size_t)i * D_ + h * 64 + tid] =
                (prt[0][tid] + prt[1][tid] + prt[2][tid] + prt[3][tid]) * inv;
        __syncthreads();
    }
}

// ---------------- attention: qa2s batched (q: A rows, kv: S rows) + probs ----------------
__global__ __launch_bounds__(128)
void attn_qa2s(const float* __restrict__ qp2, const float* __restrict__ k2,
               const float* __restrict__ v2, float* __restrict__ out,
               float* __restrict__ attn2)
{
    int bh = blockIdx.x, b = bh / NH_, h = bh % NH_;
    int tid = threadIdx.x;
    __shared__ float qv[64], sc[128], red[128], prt[2][64];
    const float* kb = k2 + (size_t)b * S_ * D_ + h * 64;
    const float* vb = v2 + (size_t)b * S_ * D_ + h * 64;
    for (int i = 0; i < A_; i++) {
        if (tid < 64) qv[tid] = qp2[((size_t)(b * A_ + i)) * D_ + h * 64 + tid];
        __syncthreads();
        {
            const float* kr = kb + (size_t)tid * D_;
            float s = 0.f;
#pragma unroll
            for (int d = 0; d < 64; d++) s = fmaf(qv[d], kr[d], s);
            sc[tid] = s * 0.125f;
        }
        __syncthreads();
        red[tid] = sc[tid]; __syncthreads();
        for (int off = 64; off > 0; off >>= 1) {
            if (tid < off) red[tid] = fmaxf(red[tid], red[tid + off]);
            __syncthreads();
        }
        float mx = red[0];
        __syncthreads();
        float e = expf(sc[tid] - mx);
        sc[tid] = e; red[tid] = e;
        __syncthreads();
        for (int off = 64; off > 0; off >>= 1) {
            if (tid < off) red[tid] += red[tid + off];
            __syncthreads();
        }
        float inv = 1.f / red[0];
        attn2[(((size_t)bh) * A_ + i) * S_ + tid] = e * inv;
        int hf = tid >> 6, d = tid & 63;
        float acc = 0.f;
        const float* vq = vb + (size_t)(hf * 64) * D_ + d;
        for (int j = 0; j < 64; j++) acc = fmaf(sc[hf * 64 + j], vq[(size_t)j * D_], acc);
        prt[hf][d] = acc;
        __syncthreads();
        if (tid < 64)
            out[((size_t)(b * A_ + i)) * D_ + h * 64 + tid] = (prt[0][tid] + prt[1][tid]) * inv;
        __syncthreads();
    }
}

__global__ void wmask_kernel(const float* __restrict__ attn2, float* __restrict__ wmask)
{
    int b = blockIdx.x;
    for (int idx = threadIdx.x; idx < A_ * S_; idx += 256) {
        float s = 0.f;
        for (int h = 0; h < NH_; h++)
            s += attn2[((size_t)(b * NH_ + h)) * A_ * S_ + idx];
        wmask[(size_t)b * A_ * S_ + idx] = s * (1.f / 12.f);
    }
}

__global__ void qa_vid_kernel(const float* __restrict__ wmask, const float* __restrict__ vid_att,
                              float* __restrict__ inputs)
{
    int idx = blockIdx.x * 256 + threadIdx.x;   // 64*768
    if (idx >= 64 * 768) return;
    int r = idx / 768, c = idx - r * 768;
    int b = r >> 3, i = r & 7;
    const float* wrow = wmask + (size_t)b * 1024 + i * 128;
    const float* vbase = vid_att + (size_t)b * S_ * D_ + c;
    float acc = 0.f;
    for (int j = 0; j < 128; j++) acc = fmaf(wrow[j], vbase[(size_t)j * D_], acc);
    inputs[(size_t)r * DIN_ + c] = acc;
}

__global__ void gather_rows(const void* __restrict__ src, float* __restrict__ dst,
                            int rows, int rpb, int t, const int* __restrict__ dtf)
{
    int f = dtf[0];
    int idx = blockIdx.x * 256 + threadIdx.x;
    if (idx >= rows * D_) return;
    int r = idx / D_, c = idx - r * D_;
    int b = r / rpb, rr = r - b * rpb;
    size_t s = (((size_t)(b * T_ + t)) * rpb + rr) * D_ + c;
    dst[idx] = ldx(src, s, f);
}

__global__ void qa_add(float* __restrict__ inputs, const float* __restrict__ q_t)
{
    int idx = blockIdx.x * 256 + threadIdx.x;   // 64*768
    if (idx >= 64 * 768) return;
    int r = idx / 768, c = idx - r * 768;
    inputs[(size_t)r * DIN_ + 1536 + c] += q_t[(size_t)(r >> 3) * 768 + c];
}

__global__ void copy_ab(const float* __restrict__ a_b, float* __restrict__ inputs)
{
    int idx = blockIdx.x * 256 + threadIdx.x;   // 320*768
    if (idx >= 320 * 768) return;
    int r = idx / 768, c = idx - r * 768;
    int row = r / 5, m = r - 5 * row;
    inputs[(size_t)row * DIN_ + 2304 + m * 768 + c] = a_b[idx];
}

__global__ void gru_elt(const float* __restrict__ gi, const float* __restrict__ gh,
                        const float* __restrict__ h, float* __restrict__ states)
{
    int idx = blockIdx.x * 256 + threadIdx.x;   // 64*768
    if (idx >= 64 * 768) return;
    int r = idx / 768, c = idx - r * 768; int b = r >> 3;
    float ir  = gi[(size_t)r * 2304 + c];
    float iz  = gi[(size_t)r * 2304 + 768 + c];
    float inn = gi[(size_t)r * 2304 + 1536 + c];
    float hr  = gh[(size_t)b * 2304 + c];
    float hz  = gh[(size_t)b * 2304 + 768 + c];
    float hn  = gh[(size_t)b * 2304 + 1536 + c];
    float hv  = h[(size_t)b * 768 + c];
    float rg = 1.f / (1.f + expf(-(ir + hr)));
    float zg = 1.f / (1.f + expf(-(iz + hz)));
    float ng = tanhf(inn + rg * hn);
    states[idx] = (1.f - zg) * ng + zg * hv;
}

__global__ void logits_kernel(const float* __restrict__ s1, const void* __restrict__ w2,
                              const void* __restrict__ b2, float* __restrict__ logits,
                              void* __restrict__ out, int t, const int* __restrict__ dtf)
{
    int f = dtf[0];
    __shared__ float red[256];
    int r = blockIdx.x;                 // 0..63
    float p = 0.f;
    for (int c = threadIdx.x; c < 768; c += 256)
        p = fmaf(s1[(size_t)r * 768 + c], ldx(w2, c, f), p);
    red[threadIdx.x] = p; __syncthreads();
    for (int off = 128; off > 0; off >>= 1) {
        if (threadIdx.x < off) red[threadIdx.x] += red[threadIdx.x + off];
        __syncthreads();
    }
    if (threadIdx.x == 0) {
        float lg = red[0] + ldx(b2, 0, f);
        logits[r] = lg;
        int b = r >> 3, a = r & 7;
        size_t o = (size_t)(b * T_ + t) * A_ + a;
        if (f) ((bf16*)out)[o] = __float2bfloat16(lg);
        else   ((float*)out)[o] = lg;
    }
}

__global__ void argmax_state(const float* __restrict__ logits, const float* __restrict__ pre,
                             float* __restrict__ hstate)
{
    __shared__ int amax;
    int b = blockIdx.x;
    if (threadIdx.x == 0) {
        float best = logits[b * 8]; int bi = 0;
        for (int a = 1; a < 8; a++) { float v = logits[b * 8 + a]; if (v > best) { best = v; bi = a; } }
        amax = bi;
    }
    __syncthreads();
    const float* src = pre + ((size_t)(b * 8 + amax)) * 768;
    for (int c = threadIdx.x; c < 768; c += 256) hstate[(size_t)b * 768 + c] = src[c];
}

__global__ void init_h(const void* __restrict__ s0, float* __restrict__ h,
                       const int* __restrict__ dtf)
{
    int f = dtf[0];
    int idx = blockIdx.x * 256 + threadIdx.x;
    if (idx >= 8 * 768) return;
    int c = idx - (idx / 768) * 768;
    h[idx] = ldx(s0, c, f);
}

// ---------------- host side ----------------
static inline void G(hipStream_t st, const void* A, long aoff, int araw, int lda,
                     const void* W, long woff, const void* bias, long boff,
                     float* C, int ldc, int M, int N, int K, int relu, const int* dtf)
{
    dim3 g(N / 64, (M + 63) / 64, 1), blk(256);
    if (relu) gemm_nt<1, true><<<g, blk, 0, st>>>(A, aoff, araw, lda, W, woff, K, bias, boff, C, ldc, M, N, K, 1, dtf);
    else      gemm_nt<0, true><<<g, blk, 0, st>>>(A, aoff, araw, lda, W, woff, K, bias, boff, C, ldc, M, N, K, 1, dtf);
}

extern "C" void kernel_launch(void* const* d_in, const int* in_sizes, int n_in,
                              void* d_out, int out_size, void* d_ws, size_t ws_size,
                              hipStream_t stream)
{
    const void* video     = d_in[0];
    const void* script    = d_in[1];
    const void* question  = d_in[2];
    const void* a_texts   = d_in[3];
    const void* a_buttons = d_in[4];
    const void* state0    = d_in[5];
    const void* mlp_v_w1 = d_in[6];  const void* mlp_v_b1 = d_in[7];
    const void* mlp_v_w2 = d_in[8];  const void* mlp_v_b2 = d_in[9];
    const void* mlp_t_w1 = d_in[10]; const void* mlp_t_b1 = d_in[11];
    const void* mlp_t_w2 = d_in[12]; const void* mlp_t_b2 = d_in[13];
    const void* pre_w1   = d_in[14]; const void* pre_b1   = d_in[15];
    const void* pre_w2   = d_in[16]; const void* pre_b2   = d_in[17];
    const void* s2v_in_w = d_in[18]; const void* s2v_in_b = d_in[19];
    const void* s2v_out_w= d_in[20]; const void* s2v_out_b= d_in[21];
    const void* qa2s_in_w= d_in[22]; const void* qa2s_in_b= d_in[23];
    const void* qa2s_out_w=d_in[24]; const void* qa2s_out_b=d_in[25];
    const void* gru_w_ih = d_in[26]; const void* gru_w_hh = d_in[27];
    const void* gru_b_ih = d_in[28]; const void* gru_b_hh = d_in[29];
    const void* proj_w1  = d_in[30]; const void* proj_b1  = d_in[31];
    const void* proj_w2  = d_in[32]; const void* proj_b2  = d_in[33];
    (void)in_sizes; (void)n_in; (void)out_size; (void)ws_size;

    // ---- compact workspace layout (~28.4 MB total) ----
    char* base = (char*)d_ws;
    int*   dtf     = (int*)base;                        // 256 B slot
    float* vid_att = (float*)(base + 256);              // 786432 f
    float* k2      = vid_att + 786432;                  // 786432 f
    float* v2      = k2      + 786432;                  // 786432 f
    float* q_t     = v2      + 786432;                  // 6144 f
    float* hstate  = q_t     + 6144;                    // 6144 f
    float* logits  = hstate  + 6144;                    // 64 f
    float* U       = logits  + 64;                      // union region: 4,724,736 f
    // phase-1 mapping of U
    float* qp      = U;                                 // 786432  (B*S*D)
    float* attnout = qp      + 786432;                  // 786432
    float* scrH    = attnout + 786432;                  // 786432
    float* scr_t   = scrH    + 786432;                  // 786432
    float* vidH_l  = scr_t   + 786432;                  // 393216  (V*D, per-sample)
    float* vid_l   = vidH_l  + 393216;                  // 393216
    float* kp_l    = vid_l   + 393216;                  // 393216
    float* vp_l    = kp_l    + 393216;                  // 393216
    float* qH      = vp_l    + 393216;                  // 6144
    // scan mapping of U (phase-1 temporaries dead by then)
    float* inputs  = U;                                 // 393216  (64*DIN)
    float* preH    = inputs  + 393216;                  // 393216
    float* part    = preH    + 393216;                  // 1572864 (4*64*DIN)
    float* at_g    = part    + 1572864;                 // 49152
    float* ab_g    = at_g    + 49152;                   // 245760
    float* a_tH    = ab_g    + 245760;                  // 49152
    float* abH     = a_tH    + 49152;                   // 245760
    float* a_b     = abH     + 245760;                  // 245760
    float* qp2     = a_b     + 245760;                  // 49152
    float* attnout2= qp2     + 49152;                   // 49152
    float* attn2   = attnout2+ 49152;                   // 98304
    float* wmask   = attn2   + 98304;                   // 8192
    float* pre     = wmask   + 8192;                    // 49152
    float* gi      = pre     + 49152;                   // 147456
    float* gh      = gi      + 147456;                  // 18432
    float* states  = gh      + 18432;                   // 49152
    float* s1      = states  + 49152;                   // 49152

    hipStream_t st = stream;
    const long DD = (long)D_ * D_;

    probe_dtype<<<1, 64, 0, st>>>(video, dtf);

    // ---- phase 1 ----
    // qp = script @ wq + bq   (batched, M = B*S = 1024)
    G(st, script, 0, 1, D_, s2v_in_w, 0, s2v_in_b, 0, qp, D_, B_ * S_, D_, D_, 0, dtf);
    for (int b = 0; b < B_; b++) {
        long vo = (long)b * V_ * D_;
        G(st, video, vo, 1, D_, mlp_v_w1, 0, mlp_v_b1, 0, vidH_l, D_, V_, D_, D_, 1, dtf);
        G(st, vidH_l, 0, 0, D_, mlp_v_w2, 0, mlp_v_b2, 0, vid_l, D_, V_, D_, D_, 0, dtf);
        G(st, vid_l, 0, 0, D_, s2v_in_w, DD,     s2v_in_b, D_,     kp_l, D_, V_, D_, D_, 0, dtf);
        G(st, vid_l, 0, 0, D_, s2v_in_w, 2 * DD, s2v_in_b, 2 * D_, vp_l, D_, V_, D_, D_, 0, dtf);
        attn_s2v<<<NH_, 256, 0, st>>>(qp + (size_t)b * S_ * D_, kp_l, vp_l,
                                      attnout + (size_t)b * S_ * D_);
    }
    G(st, attnout, 0, 0, D_, s2v_out_w, 0, s2v_out_b, 0, vid_att, D_, B_ * S_, D_, D_, 0, dtf);
    G(st, script, 0, 1, D_, mlp_t_w1, 0, mlp_t_b1, 0, scrH, D_, B_ * S_, D_, D_, 1, dtf);
    G(st, scrH, 0, 0, D_, mlp_t_w2, 0, mlp_t_b2, 0, scr_t, D_, B_ * S_, D_, D_, 0, dtf);
    G(st, question, 0, 1, D_, mlp_t_w1, 0, mlp_t_b1, 0, qH, D_, B_, D_, D_, 1, dtf);
    G(st, qH, 0, 0, D_, mlp_t_w2, 0, mlp_t_b2, 0, q_t, D_, B_, D_, D_, 0, dtf);
    // hoisted qa2s K/V projections (loop-invariant in the reference)
    G(st, scr_t, 0, 0, D_, qa2s_in_w, DD,     qa2s_in_b, D_,     k2, D_, B_ * S_, D_, D_, 0, dtf);
    G(st, scr_t, 0, 0, D_, qa2s_in_w, 2 * DD, qa2s_in_b, 2 * D_, v2, D_, B_ * S_, D_, D_, 0, dtf);
    init_h<<<24, 256, 0, st>>>(state0, hstate, dtf);

    // ---- scan over T steps ----
    for (int t = 0; t < T_; t++) {
        gather_rows<<<192, 256, 0, st>>>(a_texts, at_g, 64, A_, t, dtf);
        gather_rows<<<960, 256, 0, st>>>(a_buttons, ab_g, 320, A_ * M_, t, dtf);
        G(st, at_g, 0, 0, D_, mlp_t_w1, 0, mlp_t_b1, 0, a_tH, D_, 64, D_, D_, 1, dtf);
        G(st, a_tH, 0, 0, D_, mlp_t_w2, 0, mlp_t_b2, 0, inputs + 1536, DIN_, 64, D_, D_, 0, dtf);
        qa_add<<<192, 256, 0, st>>>(inputs, q_t);
        G(st, ab_g, 0, 0, D_, mlp_v_w1, 0, mlp_v_b1, 0, abH, D_, 320, D_, D_, 1, dtf);
        G(st, abH, 0, 0, D_, mlp_v_w2, 0, mlp_v_b2, 0, a_b, D_, 320, D_, D_, 0, dtf);
        copy_ab<<<960, 256, 0, st>>>(a_b, inputs);
        G(st, inputs + 1536, 0, 0, DIN_, qa2s_in_w, 0, qa2s_in_b, 0, qp2, D_, 64, D_, D_, 0, dtf);
        attn_qa2s<<<B_ * NH_, 128, 0, st>>>(qp2, k2, v2, attnout2, attn2);
        wmask_kernel<<<B_, 256, 0, st>>>(attn2, wmask);
        qa_vid_kernel<<<192, 256, 0, st>>>(wmask, vid_att, inputs);
        G(st, attnout2, 0, 0, D_, qa2s_out_w, 0, qa2s_out_b, 0, inputs + 768, DIN_, 64, D_, D_, 0, dtf);
        {   // pre = mlp_pre(inputs): split-K
            dim3 g1(DIN_ / 64, 1, 4);
            gemm_nt<0, false><<<g1, 256, 0, st>>>(inputs, 0, 0, DIN_, pre_w1, 0, DIN_,
                                                  nullptr, 0, part, DIN_, 64, DIN_, DIN_, 4, dtf);
            reduce_bias_act<1><<<1536, 256, 0, st>>>(part, pre_b1, 0, preH, 64, DIN_, 4, dtf);
            dim3 g2(DS_ / 64, 1, 8);
            gemm_nt<0, false><<<g2, 256, 0, st>>>(preH, 0, 0, DIN_, pre_w2, 0, DIN_,
                                                  nullptr, 0, part, DS_, 64, DS_, DIN_, 8, dtf);
            reduce_bias_act<0><<<192, 256, 0, st>>>(part, pre_b2, 0, pre, 64, DS_, 8, dtf);
        }
        G(st, pre, 0, 0, DS_, gru_w_ih, 0, gru_b_ih, 0, gi, 3 * DS_, 64, 3 * DS_, DS_, 0, dtf);
        G(st, hstate, 0, 0, DS_, gru_w_hh, 0, gru_b_hh, 0, gh, 3 * DS_, B_, 3 * DS_, DS_, 0, dtf);
        gru_elt<<<192, 256, 0, st>>>(gi, gh, hstate, states);
        G(st, states, 0, 0, DS_, proj_w1, 0, proj_b1, 0, s1, DS_, 64, DS_, DS_, 1, dtf);
        logits_kernel<<<64, 256, 0, st>>>(s1, proj_w2, proj_b2, logits, d_out, t, dtf);
        argmax_state<<<B_, 256, 0, st>>>(logits, pre, hstate);
    }
}

// Round 4
// 19584.576 us; speedup vs baseline: 1.5389x; 1.5389x over previous
//
#include <hip/hip_runtime.h>
#include <hip/hip_bf16.h>
#include <math.h>

typedef __hip_bfloat16 bf16;
typedef short s8v __attribute__((ext_vector_type(8)));
typedef float f4v __attribute__((ext_vector_type(4)));
typedef float f8v __attribute__((ext_vector_type(8)));

#define D_    768
#define M_    5
#define DS_   768
#define NH_   12
#define B_    8
#define V_    512
#define S_    128
#define T_    16
#define A_    8
#define DIN_  6144

// split fp32 x into bf16 hi (truncate) + bf16 lo (truncate of exact residual)
__device__ __forceinline__ void split8(const f8v& x, s8v& hi, s8v& lo) {
#pragma unroll
    for (int j = 0; j < 8; j++) {
        unsigned xu = __float_as_uint(x[j]);
        float hf = __uint_as_float(xu & 0xFFFF0000u);
        float r  = x[j] - hf;                       // exact in fp32
        hi[j] = (short)(xu >> 16);
        lo[j] = (short)(__float_as_uint(r) >> 16);
    }
}

// ============ split-bf16 MFMA GEMM: C = act(A @ W^T + bias [+res]) ============
// A: (M,K) fp32, generalized row addressing: row r at (r/arpb)*abst + (r%arpb)*lda + aoff.
// W: (N,K) fp32 at W+woff. Output fp32: (row/orpb)*ostride + (row%orpb)*osub + coff + col.
// SPLIT: fp32 partials to part[(z*M+row)*N+col], bias/act skipped.
// 256 thr = 4 waves; tile 64(M) x 128(N); wave w covers cols [w*32, w*32+32).
template<int ACT, bool SPLIT, bool RES>
__global__ __launch_bounds__(256)
void mm(const float* __restrict__ A, int lda, int arpb, long abst, long aoff,
        const float* __restrict__ W, long woff,
        const float* __restrict__ bias, long boff,
        float* __restrict__ Cout, int orpb, long ostride, long osub, long coff,
        const float* __restrict__ res, float* __restrict__ part,
        int M, int N, int K, int Z)
{
    const int tid = threadIdx.x;
    const int w = tid >> 6, l = tid & 63, q = l >> 4, ln = l & 15;
    const int n0 = blockIdx.x * 128 + w * 32;
    const int m0 = blockIdx.y * 64;
    const int kc = K / Z, k0 = blockIdx.z * kc, k1 = k0 + kc;

    const float* arow[4];
#pragma unroll
    for (int mf = 0; mf < 4; mf++) {
        int rm = m0 + mf * 16 + ln;
        if (rm > M - 1) rm = M - 1;
        long ro = (long)(rm / arpb) * abst + (long)(rm % arpb) * lda + aoff;
        arow[mf] = A + ro + q * 8;
    }
    const float* wrow[2];
#pragma unroll
    for (int nf = 0; nf < 2; nf++)
        wrow[nf] = W + woff + (long)(n0 + nf * 16 + ln) * K + q * 8;

    f4v acc[4][2];
#pragma unroll
    for (int mf = 0; mf < 4; mf++)
#pragma unroll
        for (int nf = 0; nf < 2; nf++)
#pragma unroll
            for (int r = 0; r < 4; r++) acc[mf][nf][r] = 0.f;

    for (int k = k0; k < k1; k += 32) {
        s8v ah[4], al[4], bh[2], bl[2];
#pragma unroll
        for (int mf = 0; mf < 4; mf++) {
            f8v av = *(const f8v*)(const void*)(arow[mf] + k);
            split8(av, ah[mf], al[mf]);
        }
#pragma unroll
        for (int nf = 0; nf < 2; nf++) {
            f8v wv = *(const f8v*)(const void*)(wrow[nf] + k);
            split8(wv, bh[nf], bl[nf]);
        }
#pragma unroll
        for (int mf = 0; mf < 4; mf++)
#pragma unroll
            for (int nf = 0; nf < 2; nf++) {
                acc[mf][nf] = __builtin_amdgcn_mfma_f32_16x16x32_bf16(ah[mf], bh[nf], acc[mf][nf], 0, 0, 0);
                acc[mf][nf] = __builtin_amdgcn_mfma_f32_16x16x32_bf16(ah[mf], bl[nf], acc[mf][nf], 0, 0, 0);
                acc[mf][nf] = __builtin_amdgcn_mfma_f32_16x16x32_bf16(al[mf], bh[nf], acc[mf][nf], 0, 0, 0);
            }
    }

#pragma unroll
    for (int mf = 0; mf < 4; mf++) {
#pragma unroll
        for (int r = 0; r < 4; r++) {
            int row = m0 + mf * 16 + q * 4 + r;
            if (row >= M) continue;
#pragma unroll
            for (int nf = 0; nf < 2; nf++) {
                int col = n0 + nf * 16 + ln;
                float v = acc[mf][nf][r];
                if (SPLIT) {
                    part[((long)blockIdx.z * M + row) * N + col] = v;
                } else {
                    v += bias[boff + col];
                    if (ACT) v = fmaxf(v, 0.f);
                    if (RES) v += res[(size_t)(row >> 3) * 768 + col];
                    long o = (long)(row / orpb) * ostride + (long)(row % orpb) * osub + coff + col;
                    Cout[o] = v;
                }
            }
        }
    }
}

template<int ACT>
__global__ void reduce_bias(const float* __restrict__ part, const float* __restrict__ bias,
                            float* __restrict__ C, int MN, int N, int Z)
{
    int idx = blockIdx.x * 256 + threadIdx.x;
    if (idx >= MN) return;
    int n = idx % N;
    float s = 0.f;
    for (int z = 0; z < Z; z++) s += part[(long)z * MN + idx];
    s += bias[n];
    if (ACT) s = fmaxf(s, 0.f);
    C[idx] = s;
}

// ============ attention: s2v, one sample (q: S rows, kv: V rows) ============
__global__ __launch_bounds__(256)
void attn_s2v(const float* __restrict__ qp_b, const float* __restrict__ kp_l,
              const float* __restrict__ vp_l, float* __restrict__ out_b)
{
    int h = blockIdx.x;
    int tid = threadIdx.x;
    __shared__ float qv[64], sc[512], red[256], prt[4][64];
    const float* kb = kp_l + h * 64;
    const float* vb = vp_l + h * 64;
    for (int i = 0; i < S_; i++) {
        if (tid < 64) qv[tid] = qp_b[(size_t)i * D_ + h * 64 + tid];
        __syncthreads();
        for (int j = tid; j < V_; j += 256) {
            const float* kr = kb + (size_t)j * D_;
            float s = 0.f;
#pragma unroll
            for (int d = 0; d < 64; d++) s = fmaf(qv[d], kr[d], s);
            sc[j] = s * 0.125f;
        }
        __syncthreads();
        red[tid] = fmaxf(sc[tid], sc[tid + 256]);
        __syncthreads();
        for (int off = 128; off > 0; off >>= 1) {
            if (tid < off) red[tid] = fmaxf(red[tid], red[tid + off]);
            __syncthreads();
        }
        float mx = red[0];
        __syncthreads();
        float e0 = expf(sc[tid] - mx), e1 = expf(sc[tid + 256] - mx);
        sc[tid] = e0; sc[tid + 256] = e1;
        red[tid] = e0 + e1;
        __syncthreads();
        for (int off = 128; off > 0; off >>= 1) {
            if (tid < off) red[tid] += red[tid + off];
            __syncthreads();
        }
        float inv = 1.f / red[0];
        int q4 = tid >> 6, d = tid & 63;
        float acc = 0.f;
        const float* vq = vb + (size_t)(q4 * 128) * D_ + d;
        for (int j = 0; j < 128; j++) acc = fmaf(sc[q4 * 128 + j], vq[(size_t)j * D_], acc);
        prt[q4][d] = acc;
        __syncthreads();
        if (tid < 64)
            out_b[(size_t)i * D_ + h * 64 + tid] =
                (prt[0][tid] + prt[1][tid] + prt[2][tid] + prt[3][tid]) * inv;
        __syncthreads();
    }
}

// ============ attention: qa2s batched (q: A rows, kv: S rows) + probs ============
__global__ __launch_bounds__(128)
void attn_qa2s(const float* __restrict__ qp2, const float* __restrict__ k2,
               const float* __restrict__ v2, float* __restrict__ out,
               float* __restrict__ attn2)
{
    int bh = blockIdx.x, b = bh / NH_, h = bh % NH_;
    int tid = threadIdx.x;
    __shared__ float qv[64], sc[128], red[128], prt[2][64];
    const float* kb = k2 + (size_t)b * S_ * D_ + h * 64;
    const float* vb = v2 + (size_t)b * S_ * D_ + h * 64;
    for (int i = 0; i < A_; i++) {
        if (tid < 64) qv[tid] = qp2[((size_t)(b * A_ + i)) * D_ + h * 64 + tid];
        __syncthreads();
        {
            const float* kr = kb + (size_t)tid * D_;
            float s = 0.f;
#pragma unroll
            for (int d = 0; d < 64; d++) s = fmaf(qv[d], kr[d], s);
            sc[tid] = s * 0.125f;
        }
        __syncthreads();
        red[tid] = sc[tid]; __syncthreads();
        for (int off = 64; off > 0; off >>= 1) {
            if (tid < off) red[tid] = fmaxf(red[tid], red[tid + off]);
            __syncthreads();
        }
        float mx = red[0];
        __syncthreads();
        float e = expf(sc[tid] - mx);
        sc[tid] = e; red[tid] = e;
        __syncthreads();
        for (int off = 64; off > 0; off >>= 1) {
            if (tid < off) red[tid] += red[tid + off];
            __syncthreads();
        }
        float inv = 1.f / red[0];
        attn2[(((size_t)bh) * A_ + i) * S_ + tid] = e * inv;
        int hf = tid >> 6, d = tid & 63;
        float acc = 0.f;
        const float* vq = vb + (size_t)(hf * 64) * D_ + d;
        for (int j = 0; j < 64; j++) acc = fmaf(sc[hf * 64 + j], vq[(size_t)j * D_], acc);
        prt[hf][d] = acc;
        __syncthreads();
        if (tid < 64)
            out[((size_t)(b * A_ + i)) * D_ + h * 64 + tid] = (prt[0][tid] + prt[1][tid]) * inv;
        __syncthreads();
    }
}

__global__ void wmask_kernel(const float* __restrict__ attn2, float* __restrict__ wmask)
{
    int b = blockIdx.x;
    for (int idx = threadIdx.x; idx < A_ * S_; idx += 256) {
        float s = 0.f;
        for (int h = 0; h < NH_; h++)
            s += attn2[((size_t)(b * NH_ + h)) * A_ * S_ + idx];
        wmask[(size_t)b * A_ * S_ + idx] = s * (1.f / 12.f);
    }
}

__global__ void qa_vid_kernel(const float* __restrict__ wmask, const float* __restrict__ vid_att,
                              float* __restrict__ inputs)
{
    int idx = blockIdx.x * 256 + threadIdx.x;   // 64*768
    if (idx >= 64 * 768) return;
    int r = idx / 768, c = idx - r * 768;
    int b = r >> 3, i = r & 7;
    const float* wrow = wmask + (size_t)b * 1024 + i * 128;
    const float* vbase = vid_att + (size_t)b * S_ * D_ + c;
    float acc = 0.f;
    for (int j = 0; j < 128; j++) acc = fmaf(wrow[j], vbase[(size_t)j * D_], acc);
    inputs[(size_t)r * DIN_ + c] = acc;
}

__global__ void gru_elt(const float* __restrict__ gi, const float* __restrict__ gh,
                        const float* __restrict__ h, float* __restrict__ states)
{
    int idx = blockIdx.x * 256 + threadIdx.x;   // 64*768
    if (idx >= 64 * 768) return;
    int r = idx / 768, c = idx - r * 768; int b = r >> 3;
    float ir  = gi[(size_t)r * 2304 + c];
    float iz  = gi[(size_t)r * 2304 + 768 + c];
    float inn = gi[(size_t)r * 2304 + 1536 + c];
    float hr  = gh[(size_t)b * 2304 + c];
    float hz  = gh[(size_t)b * 2304 + 768 + c];
    float hn  = gh[(size_t)b * 2304 + 1536 + c];
    float hv  = h[(size_t)b * 768 + c];
    float rg = 1.f / (1.f + expf(-(ir + hr)));
    float zg = 1.f / (1.f + expf(-(iz + hz)));
    float ng = tanhf(inn + rg * hn);
    states[idx] = (1.f - zg) * ng + zg * hv;
}

__global__ void logits_kernel(const float* __restrict__ s1, const float* __restrict__ w2,
                              const float* __restrict__ b2, float* __restrict__ logits,
                              float* __restrict__ out, int t)
{
    __shared__ float red[256];
    int r = blockIdx.x;                 // 0..63
    float p = 0.f;
    for (int c = threadIdx.x; c < 768; c += 256)
        p = fmaf(s1[(size_t)r * 768 + c], w2[c], p);
    red[threadIdx.x] = p; __syncthreads();
    for (int off = 128; off > 0; off >>= 1) {
        if (threadIdx.x < off) red[threadIdx.x] += red[threadIdx.x + off];
        __syncthreads();
    }
    if (threadIdx.x == 0) {
        float lg = red[0] + b2[0];
        logits[r] = lg;
        int b = r >> 3, a = r & 7;
        out[(size_t)(b * T_ + t) * A_ + a] = lg;
    }
}

__global__ void argmax_state(const float* __restrict__ logits, const float* __restrict__ pre,
                             float* __restrict__ hstate)
{
    __shared__ int amax;
    int b = blockIdx.x;
    if (threadIdx.x == 0) {
        float best = logits[b * 8]; int bi = 0;
        for (int a = 1; a < 8; a++) { float v = logits[b * 8 + a]; if (v > best) { best = v; bi = a; } }
        amax = bi;
    }
    __syncthreads();
    const float* src = pre + ((size_t)(b * 8 + amax)) * 768;
    for (int c = threadIdx.x; c < 768; c += 256) hstate[(size_t)b * 768 + c] = src[c];
}

__global__ void init_h(const float* __restrict__ s0, float* __restrict__ h)
{
    int idx = blockIdx.x * 256 + threadIdx.x;
    if (idx >= 8 * 768) return;
    h[idx] = s0[idx % 768];
}

// ============ host ============
static inline void MM(hipStream_t st, const float* A, int lda, int arpb, long abst, long aoff,
                      const float* W, long woff, const float* bias, long boff,
                      float* C, int orpb, long ostride, long osub, long coff,
                      const float* res, float* part,
                      int M, int N, int K, int Z, int relu)
{
    dim3 g(N / 128, (M + 63) / 64, Z), b(256);
    if (Z > 1)
        mm<0, true , false><<<g, b, 0, st>>>(A, lda, arpb, abst, aoff, W, woff, bias, boff, C, orpb, ostride, osub, coff, res, part, M, N, K, Z);
    else if (res)
        mm<0, false, true ><<<g, b, 0, st>>>(A, lda, arpb, abst, aoff, W, woff, bias, boff, C, orpb, ostride, osub, coff, res, part, M, N, K, Z);
    else if (relu)
        mm<1, false, false><<<g, b, 0, st>>>(A, lda, arpb, abst, aoff, W, woff, bias, boff, C, orpb, ostride, osub, coff, res, part, M, N, K, Z);
    else
        mm<0, false, false><<<g, b, 0, st>>>(A, lda, arpb, abst, aoff, W, woff, bias, boff, C, orpb, ostride, osub, coff, res, part, M, N, K, Z);
}

#define NP (1 << 30)

extern "C" void kernel_launch(void* const* d_in, const int* in_sizes, int n_in,
                              void* d_out, int out_size, void* d_ws, size_t ws_size,
                              hipStream_t stream)
{
    const float* video     = (const float*)d_in[0];
    const float* script    = (const float*)d_in[1];
    const float* question  = (const float*)d_in[2];
    const float* a_texts   = (const float*)d_in[3];
    const float* a_buttons = (const float*)d_in[4];
    const float* state0    = (const float*)d_in[5];
    const float* mlp_v_w1 = (const float*)d_in[6];  const float* mlp_v_b1 = (const float*)d_in[7];
    const float* mlp_v_w2 = (const float*)d_in[8];  const float* mlp_v_b2 = (const float*)d_in[9];
    const float* mlp_t_w1 = (const float*)d_in[10]; const float* mlp_t_b1 = (const float*)d_in[11];
    const float* mlp_t_w2 = (const float*)d_in[12]; const float* mlp_t_b2 = (const float*)d_in[13];
    const float* pre_w1   = (const float*)d_in[14]; const float* pre_b1   = (const float*)d_in[15];
    const float* pre_w2   = (const float*)d_in[16]; const float* pre_b2   = (const float*)d_in[17];
    const float* s2v_in_w = (const float*)d_in[18]; const float* s2v_in_b = (const float*)d_in[19];
    const float* s2v_out_w= (const float*)d_in[20]; const float* s2v_out_b= (const float*)d_in[21];
    const float* qa2s_in_w= (const float*)d_in[22]; const float* qa2s_in_b= (const float*)d_in[23];
    const float* qa2s_out_w=(const float*)d_in[24]; const float* qa2s_out_b=(const float*)d_in[25];
    const float* gru_w_ih = (const float*)d_in[26]; const float* gru_w_hh = (const float*)d_in[27];
    const float* gru_b_ih = (const float*)d_in[28]; const float* gru_b_hh = (const float*)d_in[29];
    const float* proj_w1  = (const float*)d_in[30]; const float* proj_b1  = (const float*)d_in[31];
    const float* proj_w2  = (const float*)d_in[32]; const float* proj_b2  = (const float*)d_in[33];
    float* out = (float*)d_out;
    (void)in_sizes; (void)n_in; (void)out_size; (void)ws_size;

    // ---- workspace layout (floats, ~28.4 MB — round-2-proven size) ----
    float* fb = (float*)d_ws;
    float* vid_att = fb;                 fb += 786432;   // 1024x768
    float* k2      = fb;                 fb += 786432;
    float* v2      = fb;                 fb += 786432;
    float* q_t     = fb;                 fb += 6144;
    float* hstate  = fb;                 fb += 6144;
    float* logits  = fb;                 fb += 64;
    float* U       = fb;                                 // union: 4,724,736 floats
    // phase-1 view
    float* qp      = U;                  // 786432 (B*S*D)
    float* attnout = qp      + 786432;   // 786432
    float* scrH    = attnout + 786432;   // 786432
    float* scr_t   = scrH    + 786432;   // 786432
    float* vidH_l  = scr_t   + 786432;   // 393216 (V*D per-sample)
    float* vid_l   = vidH_l  + 393216;   // 393216
    float* kp_l    = vid_l   + 393216;   // 393216
    float* vp_l    = kp_l    + 393216;   // 393216
    float* qH      = vp_l    + 393216;   // 6144
    // scan view (phase-1 temporaries dead by then)
    float* inputs  = U;                  // 393216 (64x6144)
    float* preH    = inputs  + 393216;   // 393216
    float* part    = preH    + 393216;   // 1572864 (4x64x6144)
    float* abH     = part    + 1572864;  // 245760
    float* a_tH    = abH     + 245760;   // 49152
    float* qp2     = a_tH    + 49152;    // 49152
    float* attnout2= qp2     + 49152;    // 49152
    float* pre     = attnout2+ 49152;    // 49152
    float* states  = pre     + 49152;    // 49152
    float* s1      = states  + 49152;    // 49152
    float* gi      = s1      + 49152;    // 147456
    float* gh      = gi      + 147456;   // 18432
    float* attn2   = gh      + 18432;    // 98304
    float* wmask   = attn2   + 98304;    // 8192

    hipStream_t st = stream;
    const long DD = (long)D_ * D_;

    // ---- phase 1 ----
    MM(st, script, D_, NP, 0, 0, s2v_in_w, 0, s2v_in_b, 0, qp, 1, D_, 0, 0, nullptr, nullptr, B_*S_, D_, D_, 1, 0);
    for (int b = 0; b < B_; b++) {
        long vo = (long)b * V_ * D_;
        MM(st, video, D_, NP, 0, vo, mlp_v_w1, 0, mlp_v_b1, 0, vidH_l, 1, D_, 0, 0, nullptr, nullptr, V_, D_, D_, 1, 1);
        MM(st, vidH_l, D_, NP, 0, 0, mlp_v_w2, 0, mlp_v_b2, 0, vid_l, 1, D_, 0, 0, nullptr, nullptr, V_, D_, D_, 1, 0);
        MM(st, vid_l, D_, NP, 0, 0, s2v_in_w, DD,   s2v_in_b, D_,   kp_l, 1, D_, 0, 0, nullptr, nullptr, V_, D_, D_, 1, 0);
        MM(st, vid_l, D_, NP, 0, 0, s2v_in_w, 2*DD, s2v_in_b, 2*D_, vp_l, 1, D_, 0, 0, nullptr, nullptr, V_, D_, D_, 1, 0);
        attn_s2v<<<NH_, 256, 0, st>>>(qp + (size_t)b * S_ * D_, kp_l, vp_l, attnout + (size_t)b * S_ * D_);
    }
    MM(st, attnout, D_, NP, 0, 0, s2v_out_w, 0, s2v_out_b, 0, vid_att, 1, D_, 0, 0, nullptr, nullptr, B_*S_, D_, D_, 1, 0);
    MM(st, script, D_, NP, 0, 0, mlp_t_w1, 0, mlp_t_b1, 0, scrH, 1, D_, 0, 0, nullptr, nullptr, B_*S_, D_, D_, 1, 1);
    MM(st, scrH, D_, NP, 0, 0, mlp_t_w2, 0, mlp_t_b2, 0, scr_t, 1, D_, 0, 0, nullptr, nullptr, B_*S_, D_, D_, 1, 0);
    MM(st, question, D_, NP, 0, 0, mlp_t_w1, 0, mlp_t_b1, 0, qH, 1, D_, 0, 0, nullptr, nullptr, B_, D_, D_, 1, 1);
    MM(st, qH, D_, NP, 0, 0, mlp_t_w2, 0, mlp_t_b2, 0, q_t, 1, D_, 0, 0, nullptr, nullptr, B_, D_, D_, 1, 0);
    MM(st, scr_t, D_, NP, 0, 0, qa2s_in_w, DD,   qa2s_in_b, D_,   k2, 1, D_, 0, 0, nullptr, nullptr, B_*S_, D_, D_, 1, 0);
    MM(st, scr_t, D_, NP, 0, 0, qa2s_in_w, 2*DD, qa2s_in_b, 2*D_, v2, 1, D_, 0, 0, nullptr, nullptr, B_*S_, D_, D_, 1, 0);
    init_h<<<24, 256, 0, st>>>(state0, hstate);

    // ---- scan over T steps ----
    for (int t = 0; t < T_; t++) {
        // a_t = mlp_t(a_texts[:,t]) fused gather; second layer fused +q_t -> inputs[:,1536:2304]
        MM(st, a_texts, D_, A_, (long)T_*A_*D_, (long)t*A_*D_, mlp_t_w1, 0, mlp_t_b1, 0, a_tH, 1, D_, 0, 0, nullptr, nullptr, 64, D_, D_, 1, 1);
        MM(st, a_tH, D_, NP, 0, 0, mlp_t_w2, 0, mlp_t_b2, 0, inputs, 1, DIN_, 0, 1536, q_t, nullptr, 64, D_, D_, 1, 0);
        // a_b = mlp_v(a_buttons[:,t]) fused gather; scatter to inputs[:,2304:6144]
        MM(st, a_buttons, D_, A_*M_, (long)T_*A_*M_*D_, (long)t*A_*M_*D_, mlp_v_w1, 0, mlp_v_b1, 0, abH, 1, D_, 0, 0, nullptr, nullptr, 320, D_, D_, 1, 1);
        MM(st, abH, D_, NP, 0, 0, mlp_v_w2, 0, mlp_v_b2, 0, inputs, M_, DIN_, D_, 2304, nullptr, nullptr, 320, D_, D_, 1, 0);
        // qa2s attention
        MM(st, inputs + 1536, DIN_, NP, 0, 0, qa2s_in_w, 0, qa2s_in_b, 0, qp2, 1, D_, 0, 0, nullptr, nullptr, 64, D_, D_, 1, 0);
        attn_qa2s<<<B_*NH_, 128, 0, st>>>(qp2, k2, v2, attnout2, attn2);
        wmask_kernel<<<B_, 256, 0, st>>>(attn2, wmask);
        qa_vid_kernel<<<192, 256, 0, st>>>(wmask, vid_att, inputs);
        MM(st, attnout2, D_, NP, 0, 0, qa2s_out_w, 0, qa2s_out_b, 0, inputs, 1, DIN_, 0, 768, nullptr, nullptr, 64, D_, D_, 1, 0);
        // pre-MLP (split-K)
        MM(st, inputs, DIN_, NP, 0, 0, pre_w1, 0, nullptr, 0, nullptr, 1, 0, 0, 0, nullptr, part, 64, DIN_, DIN_, 4, 0);
        reduce_bias<1><<<1536, 256, 0, st>>>(part, pre_b1, preH, 64*DIN_, DIN_, 4);
        MM(st, preH, DIN_, NP, 0, 0, pre_w2, 0, nullptr, 0, nullptr, 1, 0, 0, 0, nullptr, part, 64, DS_, DIN_, 8, 0);
        reduce_bias<0><<<192, 256, 0, st>>>(part, pre_b2, pre, 64*DS_, DS_, 8);
        // GRU
        MM(st, pre, DS_, NP, 0, 0, gru_w_ih, 0, gru_b_ih, 0, gi, 1, 3*DS_, 0, 0, nullptr, nullptr, 64, 3*DS_, DS_, 1, 0);
        MM(st, hstate, DS_, NP, 0, 0, gru_w_hh, 0, gru_b_hh, 0, gh, 1, 3*DS_, 0, 0, nullptr, nullptr, B_, 3*DS_, DS_, 1, 0);
        gru_elt<<<192, 256, 0, st>>>(gi, gh, hstate, states);
        // proj + argmax state feedback
        MM(st, states, DS_, NP, 0, 0, proj_w1, 0, proj_b1, 0, s1, 1, DS_, 0, 0, nullptr, nullptr, 64, DS_, DS_, 1, 1);
        logits_kernel<<<64, 256, 0, st>>>(s1, proj_w2, proj_b2, logits, out, t);
        argmax_state<<<B_, 256, 0, st>>>(logits, pre, hstate);
    }
}

// Round 5
// 10757.413 us; speedup vs baseline: 2.8018x; 1.8206x over previous
//
#include <hip/hip_runtime.h>
#include <hip/hip_bf16.h>
#include <math.h>

typedef short s8v __attribute__((ext_vector_type(8)));
typedef float f4v __attribute__((ext_vector_type(4)));
typedef float f8v __attribute__((ext_vector_type(8)));

#define D_    768
#define M_    5
#define DS_   768
#define NH_   12
#define B_    8
#define V_    512
#define S_    128
#define T_    16
#define A_    8
#define DIN_  6144
#define NP    (1 << 30)

// split fp32 x into bf16 hi (truncate) + bf16 lo (truncate of exact residual)
__device__ __forceinline__ void split8(const f8v& x, s8v& hi, s8v& lo) {
#pragma unroll
    for (int j = 0; j < 8; j++) {
        unsigned xu = __float_as_uint(x[j]);
        float hf = __uint_as_float(xu & 0xFFFF0000u);
        float r  = x[j] - hf;                       // exact in fp32
        hi[j] = (short)(xu >> 16);
        lo[j] = (short)(__float_as_uint(r) >> 16);
    }
}

// ===== generalized split-bf16 MFMA GEMM: C = act(scale*(A @ W^T) + bias [+res]) =====
// A row r (within z-slice): A + ab + aoff + (r/arpb)*abst + (r%arpb)*lda,  frag k-offset added.
// z-batch (non-SPLIT): zh=z/zdiv, zl=z%zdiv: ab=zh*az1+zl*az2, wb=zh*wz1+zl*wz2, ob=zh*oz1+zl*oz2.
// W row n: W + woff + wb + n*ldw. Out: ob + (row/orpb)*ostride + (row%orpb)*osub + coff + col*cscale.
// SPLIT: z is the K-split index; fp32 partials to part[(z*M+row)*N+col].
// 256 thr = 4 waves; tile 64(M) x 128(N); wave w covers cols [w*32, w*32+32).
template<int ACT, bool SPLIT, bool RES>
__global__ __launch_bounds__(256)
void mm(const float* __restrict__ A, int lda, int arpb, long abst, long aoff,
        long az1, long az2, int zdiv,
        const float* __restrict__ W, long woff, int ldw, long wz1, long wz2,
        const float* __restrict__ bias, long boff, float scale,
        float* __restrict__ Cout, long oz1, long oz2, int orpb, long ostride, long osub,
        long coff, long cscale,
        const float* __restrict__ res, float* __restrict__ part,
        int M, int N, int K, int Z)
{
    const int tid = threadIdx.x;
    const int w = tid >> 6, l = tid & 63, q = l >> 4, ln = l & 15;
    const int n0 = blockIdx.x * 128 + w * 32;
    const int m0 = blockIdx.y * 64;
    const int z = blockIdx.z;
    long ab = 0, wb = 0, ob = 0;
    int k0 = 0, k1 = K;
    if (SPLIT) {
        int kc = K / Z; k0 = z * kc; k1 = k0 + kc;
    } else {
        int zh = z / zdiv, zl = z - zh * zdiv;
        ab = (long)zh * az1 + (long)zl * az2;
        wb = (long)zh * wz1 + (long)zl * wz2;
        ob = (long)zh * oz1 + (long)zl * oz2;
    }

    const float* arow[4];
#pragma unroll
    for (int mf = 0; mf < 4; mf++) {
        int rm = m0 + mf * 16 + ln;
        if (rm > M - 1) rm = M - 1;
        long ro = ab + aoff + (long)(rm / arpb) * abst + (long)(rm % arpb) * lda;
        arow[mf] = A + ro + q * 8;
    }
    const float* wrow[2];
#pragma unroll
    for (int nf = 0; nf < 2; nf++)
        wrow[nf] = W + woff + wb + (long)(n0 + nf * 16 + ln) * ldw + q * 8;

    f4v acc[4][2];
#pragma unroll
    for (int mf = 0; mf < 4; mf++)
#pragma unroll
        for (int nf = 0; nf < 2; nf++)
#pragma unroll
            for (int r = 0; r < 4; r++) acc[mf][nf][r] = 0.f;

    for (int k = k0; k < k1; k += 32) {
        s8v ah[4], al[4], bh[2], bl[2];
#pragma unroll
        for (int mf = 0; mf < 4; mf++) {
            f8v av = *(const f8v*)(const void*)(arow[mf] + k);
            split8(av, ah[mf], al[mf]);
        }
#pragma unroll
        for (int nf = 0; nf < 2; nf++) {
            f8v wv = *(const f8v*)(const void*)(wrow[nf] + k);
            split8(wv, bh[nf], bl[nf]);
        }
#pragma unroll
        for (int mf = 0; mf < 4; mf++)
#pragma unroll
            for (int nf = 0; nf < 2; nf++) {
                acc[mf][nf] = __builtin_amdgcn_mfma_f32_16x16x32_bf16(ah[mf], bh[nf], acc[mf][nf], 0, 0, 0);
                acc[mf][nf] = __builtin_amdgcn_mfma_f32_16x16x32_bf16(ah[mf], bl[nf], acc[mf][nf], 0, 0, 0);
                acc[mf][nf] = __builtin_amdgcn_mfma_f32_16x16x32_bf16(al[mf], bh[nf], acc[mf][nf], 0, 0, 0);
            }
    }

#pragma unroll
    for (int mf = 0; mf < 4; mf++) {
#pragma unroll
        for (int r = 0; r < 4; r++) {
            int row = m0 + mf * 16 + q * 4 + r;
            if (row >= M) continue;
#pragma unroll
            for (int nf = 0; nf < 2; nf++) {
                int col = n0 + nf * 16 + ln;
                if (col >= N) continue;
                float v = acc[mf][nf][r];
                if (SPLIT) {
                    part[((long)z * M + row) * N + col] = v;
                } else {
                    v *= scale;
                    if (bias) v += bias[boff + col];
                    if (ACT) v = fmaxf(v, 0.f);
                    if (RES) v += res[(size_t)(row >> 3) * 768 + col];
                    long o = ob + (long)(row / orpb) * ostride + (long)(row % orpb) * osub
                           + coff + (long)col * cscale;
                    Cout[o] = v;
                }
            }
        }
    }
}

template<int ACT>
__global__ void reduce_bias(const float* __restrict__ part, const float* __restrict__ bias,
                            float* __restrict__ C, int MN, int N, int Z)
{
    int idx = blockIdx.x * 256 + threadIdx.x;
    if (idx >= MN) return;
    int n = idx % N;
    float s = 0.f;
    for (int z = 0; z < Z; z++) s += part[(long)z * MN + idx];
    s += bias[n];
    if (ACT) s = fmaxf(s, 0.f);
    C[idx] = s;
}

// row-wise in-place softmax; grid.x = #rows, 256 threads
__global__ void softmax_rows(float* __restrict__ sc, int len)
{
    float* p = sc + (size_t)blockIdx.x * len;
    __shared__ float red[256];
    int tid = threadIdx.x;
    float m = -1e30f;
    for (int i = tid; i < len; i += 256) m = fmaxf(m, p[i]);
    red[tid] = m; __syncthreads();
    for (int o = 128; o > 0; o >>= 1) {
        if (tid < o) red[tid] = fmaxf(red[tid], red[tid + o]);
        __syncthreads();
    }
    float mx = red[0]; __syncthreads();
    float s = 0.f;
    for (int i = tid; i < len; i += 256) { float e = expf(p[i] - mx); p[i] = e; s += e; }
    red[tid] = s; __syncthreads();
    for (int o = 128; o > 0; o >>= 1) {
        if (tid < o) red[tid] += red[tid + o];
        __syncthreads();
    }
    float inv = 1.f / red[0]; __syncthreads();
    for (int i = tid; i < len; i += 256) p[i] *= inv;
}

// wmask[b][i][j] = mean_h sc2[(b*12+h)*1024 + i*128 + j]
__global__ void wmask_kernel(const float* __restrict__ sc2, float* __restrict__ wmask)
{
    int b = blockIdx.x;
    for (int idx = threadIdx.x; idx < A_ * S_; idx += 256) {
        float s = 0.f;
        for (int h = 0; h < NH_; h++) s += sc2[((size_t)(b * NH_ + h)) * 1024 + idx];
        wmask[(size_t)b * 1024 + idx] = s * (1.f / 12.f);
    }
}

__global__ void gru_elt(const float* __restrict__ gi, const float* __restrict__ gh,
                        const float* __restrict__ h, float* __restrict__ states)
{
    int idx = blockIdx.x * 256 + threadIdx.x;   // 64*768
    if (idx >= 64 * 768) return;
    int r = idx / 768, c = idx - r * 768; int b = r >> 3;
    float ir  = gi[(size_t)r * 2304 + c];
    float iz  = gi[(size_t)r * 2304 + 768 + c];
    float inn = gi[(size_t)r * 2304 + 1536 + c];
    float hr  = gh[(size_t)b * 2304 + c];
    float hz  = gh[(size_t)b * 2304 + 768 + c];
    float hn  = gh[(size_t)b * 2304 + 1536 + c];
    float hv  = h[(size_t)b * 768 + c];
    float rg = 1.f / (1.f + expf(-(ir + hr)));
    float zg = 1.f / (1.f + expf(-(iz + hz)));
    float ng = tanhf(inn + rg * hn);
    states[idx] = (1.f - zg) * ng + zg * hv;
}

// single block: logits = s1 @ w2 + b2; write out; per-sample argmax; hstate = pre[argmax]
__global__ void logits_argmax(const float* __restrict__ s1, const float* __restrict__ w2,
                              const float* __restrict__ b2, const float* __restrict__ pre,
                              float* __restrict__ hstate, float* __restrict__ out, int t)
{
    __shared__ float red[256], lg[64];
    __shared__ int am[8];
    int tid = threadIdx.x, r = tid >> 2, p = tid & 3;
    float s = 0.f;
    const float* row = s1 + (size_t)r * 768 + p * 192;
    const float* wp = w2 + p * 192;
    for (int i = 0; i < 192; i++) s = fmaf(row[i], wp[i], s);
    red[tid] = s; __syncthreads();
    if (p == 0) {
        float v = red[tid] + red[tid + 1] + red[tid + 2] + red[tid + 3] + b2[0];
        lg[r] = v;
        out[((size_t)((r >> 3) * T_ + t)) * A_ + (r & 7)] = v;
    }
    __syncthreads();
    if (tid < 8) {
        float best = lg[tid * 8]; int bi = 0;
        for (int a = 1; a < 8; a++) { float v = lg[tid * 8 + a]; if (v > best) { best = v; bi = a; } }
        am[tid] = bi;
    }
    __syncthreads();
    for (int i = tid; i < 8 * 768; i += 256) {
        int b = i / 768, c = i - b * 768;
        hstate[i] = pre[((size_t)(b * 8 + am[b])) * 768 + c];
    }
}

__global__ void init_h(const float* __restrict__ s0, float* __restrict__ h)
{
    int idx = blockIdx.x * 256 + threadIdx.x;
    if (idx >= 8 * 768) return;
    h[idx] = s0[idx % 768];
}

// ===== host =====
// plain GEMM (no batch): C[row*ldc + coff + col] = act(A@W^T + bias)
static inline void MMstd(hipStream_t st, const float* A, int lda, int arpb, long abst, long aoff,
                         const float* W, long woff, int ldw, const float* bias, long boff,
                         float* C, long ldc, long coff, int M, int N, int K, int relu)
{
    dim3 g((N + 127) / 128, (M + 63) / 64, 1), b(256);
    if (relu)
        mm<1, false, false><<<g, b, 0, st>>>(A, lda, arpb, abst, aoff, 0, 0, 1, W, woff, ldw, 0, 0,
                                             bias, boff, 1.f, C, 0, 0, 1, ldc, 0, coff, 1,
                                             nullptr, nullptr, M, N, K, 1);
    else
        mm<0, false, false><<<g, b, 0, st>>>(A, lda, arpb, abst, aoff, 0, 0, 1, W, woff, ldw, 0, 0,
                                             bias, boff, 1.f, C, 0, 0, 1, ldc, 0, coff, 1,
                                             nullptr, nullptr, M, N, K, 1);
}

extern "C" void kernel_launch(void* const* d_in, const int* in_sizes, int n_in,
                              void* d_out, int out_size, void* d_ws, size_t ws_size,
                              hipStream_t stream)
{
    const float* video     = (const float*)d_in[0];
    const float* script    = (const float*)d_in[1];
    const float* question  = (const float*)d_in[2];
    const float* a_texts   = (const float*)d_in[3];
    const float* a_buttons = (const float*)d_in[4];
    const float* state0    = (const float*)d_in[5];
    const float* mlp_v_w1 = (const float*)d_in[6];  const float* mlp_v_b1 = (const float*)d_in[7];
    const float* mlp_v_w2 = (const float*)d_in[8];  const float* mlp_v_b2 = (const float*)d_in[9];
    const float* mlp_t_w1 = (const float*)d_in[10]; const float* mlp_t_b1 = (const float*)d_in[11];
    const float* mlp_t_w2 = (const float*)d_in[12]; const float* mlp_t_b2 = (const float*)d_in[13];
    const float* pre_w1   = (const float*)d_in[14]; const float* pre_b1   = (const float*)d_in[15];
    const float* pre_w2   = (const float*)d_in[16]; const float* pre_b2   = (const float*)d_in[17];
    const float* s2v_in_w = (const float*)d_in[18]; const float* s2v_in_b = (const float*)d_in[19];
    const float* s2v_out_w= (const float*)d_in[20]; const float* s2v_out_b= (const float*)d_in[21];
    const float* qa2s_in_w= (const float*)d_in[22]; const float* qa2s_in_b= (const float*)d_in[23];
    const float* qa2s_out_w=(const float*)d_in[24]; const float* qa2s_out_b=(const float*)d_in[25];
    const float* gru_w_ih = (const float*)d_in[26]; const float* gru_w_hh = (const float*)d_in[27];
    const float* gru_b_ih = (const float*)d_in[28]; const float* gru_b_hh = (const float*)d_in[29];
    const float* proj_w1  = (const float*)d_in[30]; const float* proj_b1  = (const float*)d_in[31];
    const float* proj_w2  = (const float*)d_in[32]; const float* proj_b2  = (const float*)d_in[33];
    float* out = (float*)d_out;
    (void)in_sizes; (void)n_in; (void)out_size;

    // ---- fixed region (floats) ----
    float* fb = (float*)d_ws;
    float* vid_attT = fb;              fb += 786432;   // per b: [c=768][j=128]
    float* k2       = fb;              fb += 786432;   // row-major 1024x768
    float* v2T      = fb;              fb += 786432;   // per (b,h): [d=64][j=128]
    float* q_t      = fb;              fb += 6144;
    float* hstate   = fb;              fb += 6144;
    float* sc2      = fb;              fb += 98304;    // per (b,h): 8x128
    float* wmask    = fb;              fb += 8192;
    float* U        = fb;

    // group size g for phase-1 batching, bounded by ws_size
    size_t fixedF = 2478080, scanF = 3852288;
    int g = 1;
    for (int cand = 8; cand >= 1; cand >>= 1) {
        size_t uF = 1572864 + (size_t)cand * 1966080;
        if (uF < scanF) uF = scanF;
        if ((fixedF + uF) * 4 + 4096 <= ws_size) { g = cand; break; }
        if (cand == 1) g = 1;
    }

    // phase-1 view of U
    float* qp      = U;                   // 1024x768
    float* attnout = U + 786432;          // 1024x768
    float* bufA    = U + 1572864;                        // g*512x768 (vidH, then kp)
    float* bufB    = bufA + (size_t)g * 393216;          // g*512x768 (vid)
    float* bufD    = bufB + (size_t)g * 393216;          // vpT: per (lb,h): [d=64][j=512]
    float* sc_g    = bufD + (size_t)g * 393216;          // per z: 128x512
    float* scrH    = U + 1572864;                        // reuse group region after groups
    float* scr_t   = scrH + 786432;
    float* qH      = scrH;                               // reuse after scr_t computed
    // scan view of U
    float* inputs  = U;                  // 64x6144
    float* preH    = inputs  + 393216;   // 64x6144
    float* part    = preH    + 393216;   // 2359296 (Z=6 x 64 x 6144)
    float* abH     = part    + 2359296;  // 320x768
    float* a_tH    = abH     + 245760;   // 64x768
    float* qp2     = a_tH    + 49152;
    float* attnout2= qp2     + 49152;
    float* pre     = attnout2+ 49152;
    float* states  = pre     + 49152;
    float* s1      = states  + 49152;
    float* gi      = s1      + 49152;    // 64x2304
    float* gh      = gi      + 147456;   // 8x2304

    hipStream_t st = stream;
    const long DD = (long)D_ * D_;
    dim3 blk(256);

    // ======== phase 1 ========
    MMstd(st, script, D_, NP, 0, 0, s2v_in_w, 0, D_, s2v_in_b, 0, qp, D_, 0, B_*S_, D_, D_, 0);
    for (int s0 = 0; s0 < B_; s0 += g) {
        int Mg = 512 * g;
        long voff = (long)s0 * 393216;
        MMstd(st, video, D_, NP, 0, voff, mlp_v_w1, 0, D_, mlp_v_b1, 0, bufA, D_, 0, Mg, D_, D_, 1);
        MMstd(st, bufA, D_, NP, 0, 0, mlp_v_w2, 0, D_, mlp_v_b2, 0, bufB, D_, 0, Mg, D_, D_, 0);
        MMstd(st, bufB, D_, NP, 0, 0, s2v_in_w, DD, D_, s2v_in_b, D_, bufA, D_, 0, Mg, D_, D_, 0); // kp
        {   // vpT: out o = (row/512)*393216 + row%512 + col*512
            dim3 gr(6, (unsigned)(Mg / 64), 1);
            mm<0, false, false><<<gr, blk, 0, st>>>(bufB, D_, NP, 0, 0, 0, 0, 1,
                s2v_in_w, 2*DD, D_, 0, 0, s2v_in_b, 2*D_, 1.f,
                bufD, 0, 0, 512, 393216, 1, 0, 512, nullptr, nullptr, Mg, D_, D_, 1);
        }
        {   // scores: sc_g[z=lb*12+h][i][j] = 0.125 * qp_row_i . kp_row_j   (dh slice h)
            dim3 gr(4, 2, (unsigned)(12 * g));
            mm<0, false, false><<<gr, blk, 0, st>>>(qp, D_, NP, 0, (long)s0 * 98304, 98304, 64, 12,
                bufA, 0, D_, 393216, 64, nullptr, 0, 0.125f,
                sc_g, 786432, 65536, 1, 512, 0, 0, 1, nullptr, nullptr, S_, V_, 64, 1);
        }
        softmax_rows<<<dim3((unsigned)(12 * g * 128)), blk, 0, st>>>(sc_g, 512);
        {   // PV: attnout[b*128+i][h*64+d] = P . V
            dim3 gr(1, 2, (unsigned)(12 * g));
            mm<0, false, false><<<gr, blk, 0, st>>>(sc_g, 512, NP, 0, 0, 786432, 65536, 12,
                bufD, 0, 512, 393216, 32768, nullptr, 0, 1.f,
                attnout, 98304, 64, 1, 768, 0, (long)s0 * 98304, 1, nullptr, nullptr, S_, 64, 512, 1);
        }
    }
    {   // vid_attT: out o = (row/128)*98304 + row%128 + col*128
        dim3 gr(6, 16, 1);
        mm<0, false, false><<<gr, blk, 0, st>>>(attnout, D_, NP, 0, 0, 0, 0, 1,
            s2v_out_w, 0, D_, 0, 0, s2v_out_b, 0, 1.f,
            vid_attT, 0, 0, 128, 98304, 1, 0, 128, nullptr, nullptr, B_*S_, D_, D_, 1);
    }
    MMstd(st, script, D_, NP, 0, 0, mlp_t_w1, 0, D_, mlp_t_b1, 0, scrH, D_, 0, B_*S_, D_, D_, 1);
    MMstd(st, scrH, D_, NP, 0, 0, mlp_t_w2, 0, D_, mlp_t_b2, 0, scr_t, D_, 0, B_*S_, D_, D_, 0);
    MMstd(st, scr_t, D_, NP, 0, 0, qa2s_in_w, DD, D_, qa2s_in_b, D_, k2, D_, 0, B_*S_, D_, D_, 0);
    {   // v2T: out o = (row/128)*98304 + row%128 + col*128
        dim3 gr(6, 16, 1);
        mm<0, false, false><<<gr, blk, 0, st>>>(scr_t, D_, NP, 0, 0, 0, 0, 1,
            qa2s_in_w, 2*DD, D_, 0, 0, qa2s_in_b, 2*D_, 1.f,
            v2T, 0, 0, 128, 98304, 1, 0, 128, nullptr, nullptr, B_*S_, D_, D_, 1);
    }
    MMstd(st, question, D_, NP, 0, 0, mlp_t_w1, 0, D_, mlp_t_b1, 0, qH, D_, 0, B_, D_, D_, 1);
    MMstd(st, qH, D_, NP, 0, 0, mlp_t_w2, 0, D_, mlp_t_b2, 0, q_t, D_, 0, B_, D_, D_, 0);
    init_h<<<24, blk, 0, st>>>(state0, hstate);

    // ======== scan over T steps ========
    for (int t = 0; t < T_; t++) {
        // a_t = mlp_t(a_texts[:,t]) (fused gather); layer2 + q_t -> inputs[:,1536:2304]
        MMstd(st, a_texts, D_, A_, (long)T_*A_*D_, (long)t*A_*D_, mlp_t_w1, 0, D_, mlp_t_b1, 0,
              a_tH, D_, 0, 64, D_, D_, 1);
        {
            dim3 gr(6, 1, 1);
            mm<0, false, true><<<gr, blk, 0, st>>>(a_tH, D_, NP, 0, 0, 0, 0, 1,
                mlp_t_w2, 0, D_, 0, 0, mlp_t_b2, 0, 1.f,
                inputs, 0, 0, 1, DIN_, 0, 1536, 1, q_t, nullptr, 64, D_, D_, 1);
        }
        // a_b = mlp_v(a_buttons[:,t]) (fused gather); scatter to inputs[:,2304:6144]
        MMstd(st, a_buttons, D_, A_*M_, (long)T_*A_*M_*D_, (long)t*A_*M_*D_, mlp_v_w1, 0, D_,
              mlp_v_b1, 0, abH, D_, 0, 320, D_, D_, 1);
        {
            dim3 gr(6, 5, 1);
            mm<0, false, false><<<gr, blk, 0, st>>>(abH, D_, NP, 0, 0, 0, 0, 1,
                mlp_v_w2, 0, D_, 0, 0, mlp_v_b2, 0, 1.f,
                inputs, 0, 0, M_, DIN_, D_, 2304, 1, nullptr, nullptr, 320, D_, D_, 1);
        }
        // qa2s attention (MFMA, batched over 96 (b,h))
        MMstd(st, inputs, DIN_, NP, 0, 1536, qa2s_in_w, 0, D_, qa2s_in_b, 0, qp2, D_, 0, 64, D_, D_, 0);
        {   // scores2
            dim3 gr(1, 1, 96);
            mm<0, false, false><<<gr, blk, 0, st>>>(qp2, D_, NP, 0, 0, 6144, 64, 12,
                k2, 0, D_, 98304, 64, nullptr, 0, 0.125f,
                sc2, 12288, 1024, 1, 128, 0, 0, 1, nullptr, nullptr, A_, S_, 64, 1);
        }
        softmax_rows<<<768, blk, 0, st>>>(sc2, 128);
        wmask_kernel<<<B_, blk, 0, st>>>(sc2, wmask);
        {   // qa_vid = wmask @ vid_att -> inputs[:,0:768]
            dim3 gr(6, 1, 8);
            mm<0, false, false><<<gr, blk, 0, st>>>(wmask, 128, NP, 0, 0, 1024, 0, 1,
                vid_attT, 0, 128, 98304, 0, nullptr, 0, 1.f,
                inputs, 49152, 0, 1, DIN_, 0, 0, 1, nullptr, nullptr, A_, D_, S_, 1);
        }
        {   // PV2 -> attnout2
            dim3 gr(1, 1, 96);
            mm<0, false, false><<<gr, blk, 0, st>>>(sc2, 128, NP, 0, 0, 12288, 1024, 12,
                v2T, 0, 128, 98304, 8192, nullptr, 0, 1.f,
                attnout2, 6144, 64, 1, 768, 0, 0, 1, nullptr, nullptr, A_, 64, S_, 1);
        }
        MMstd(st, attnout2, D_, NP, 0, 0, qa2s_out_w, 0, D_, qa2s_out_b, 0, inputs, DIN_, 768, 64, D_, D_, 0);
        // pre-MLP (split-K)
        {
            dim3 gr(48, 1, 6);
            mm<0, true, false><<<gr, blk, 0, st>>>(inputs, DIN_, NP, 0, 0, 0, 0, 1,
                pre_w1, 0, DIN_, 0, 0, nullptr, 0, 1.f,
                nullptr, 0, 0, 1, 0, 0, 0, 1, nullptr, part, 64, DIN_, DIN_, 6);
        }
        reduce_bias<1><<<1536, blk, 0, st>>>(part, pre_b1, preH, 64*DIN_, DIN_, 6);
        {
            dim3 gr(6, 1, 16);
            mm<0, true, false><<<gr, blk, 0, st>>>(preH, DIN_, NP, 0, 0, 0, 0, 1,
                pre_w2, 0, DIN_, 0, 0, nullptr, 0, 1.f,
                nullptr, 0, 0, 1, 0, 0, 0, 1, nullptr, part, 64, DS_, DIN_, 16);
        }
        reduce_bias<0><<<192, blk, 0, st>>>(part, pre_b2, pre, 64*DS_, DS_, 16);
        // GRU
        MMstd(st, pre, DS_, NP, 0, 0, gru_w_ih, 0, DS_, gru_b_ih, 0, gi, 3*DS_, 0, 64, 3*DS_, DS_, 0);
        MMstd(st, hstate, DS_, NP, 0, 0, gru_w_hh, 0, DS_, gru_b_hh, 0, gh, 3*DS_, 0, B_, 3*DS_, DS_, 0);
        gru_elt<<<192, blk, 0, st>>>(gi, gh, hstate, states);
        // proj + fused logits/argmax/state-feedback
        MMstd(st, states, DS_, NP, 0, 0, proj_w1, 0, DS_, proj_b1, 0, s1, DS_, 0, 64, DS_, DS_, 1);
        logits_argmax<<<1, blk, 0, st>>>(s1, proj_w2, proj_b2, pre, hstate, out, t);
    }
}